// Round 6
// baseline (220.079 us; speedup 1.0000x reference)
//
#include <hip/hip_runtime.h>
#include <hip/hip_bf16.h>

// ---------------------------------------------------------------------------
// CompGCN layer:
//   bf16 data plane, CSR-by-(dst,half) counting sort (ILP x4 hist/rank),
//   per-bucket register aggregation, bf16-MFMA fused 3-way GEMM with
//   BN-stats fused into the epilogue, BN apply + ReLU, out_rel = rel @ w_rel.
// ---------------------------------------------------------------------------

#define SCAN_BLOCK 256

typedef __attribute__((ext_vector_type(8))) short short8v;   // 8 bf16 (4 VGPRs)
typedef __attribute__((ext_vector_type(4))) float float4v;   // MFMA C/D

__device__ inline short f2bf(float f) {
    union { float f; unsigned u; } c; c.f = f;
    unsigned u = c.u;
    return (short)((u + 0x7fffu + ((u >> 16) & 1u)) >> 16);  // RNE
}
__device__ inline float bflo(unsigned u) { return __uint_as_float(u << 16); }
__device__ inline float bfhi(unsigned u) { return __uint_as_float(u & 0xffff0000u); }

// cast x [V,128] and rel [R,128] to bf16, 8 elems/thread
__global__ __launch_bounds__(256) void xcast_kernel(
    const float* __restrict__ x, const float* __restrict__ rel,
    short* __restrict__ xbf, short* __restrict__ relbf, int V, int R)
{
    size_t i = ((size_t)blockIdx.x * 256 + threadIdx.x) * 8;
    size_t nx = (size_t)V * 128;
    size_t total = nx + (size_t)R * 128;
    if (i >= total) return;
    const float* sp; short* dp; size_t k;
    if (i < nx) { sp = x; dp = xbf; k = i; }
    else        { sp = rel; dp = relbf; k = i - nx; }
    float4 v0 = *reinterpret_cast<const float4*>(sp + k);
    float4 v1 = *reinterpret_cast<const float4*>(sp + k + 4);
    short8v o;
    o[0] = f2bf(v0.x); o[1] = f2bf(v0.y); o[2] = f2bf(v0.z); o[3] = f2bf(v0.w);
    o[4] = f2bf(v1.x); o[5] = f2bf(v1.y); o[6] = f2bf(v1.z); o[7] = f2bf(v1.w);
    *reinterpret_cast<short8v*>(dp + k) = o;
}

// 4 edges/thread: 4 independent atomic chains in flight
__global__ __launch_bounds__(256) void hist_kernel(
    const int* __restrict__ dst, int* __restrict__ cnt, int E, int V)
{
    int base = (blockIdx.x * 256 + threadIdx.x) * 4;
    if (base >= E) return;
    if (base + 3 < E) {
        int4 d = *reinterpret_cast<const int4*>(dst + base);
        int half = E >> 1;
        atomicAdd(&cnt[d.x + (base + 0 < half ? 0 : V)], 1);
        atomicAdd(&cnt[d.y + (base + 1 < half ? 0 : V)], 1);
        atomicAdd(&cnt[d.z + (base + 2 < half ? 0 : V)], 1);
        atomicAdd(&cnt[d.w + (base + 3 < half ? 0 : V)], 1);
    } else {
        for (int e = base; e < E; ++e)
            atomicAdd(&cnt[dst[e] + (e < (E >> 1) ? 0 : V)], 1);
    }
}

__global__ __launch_bounds__(SCAN_BLOCK) void scan_partial_kernel(
    const int* __restrict__ cnt, int* __restrict__ partials, int N)
{
    __shared__ int red[SCAN_BLOCK];
    int i = blockIdx.x * SCAN_BLOCK + threadIdx.x;
    red[threadIdx.x] = (i < N) ? cnt[i] : 0;
    __syncthreads();
    for (int s = SCAN_BLOCK / 2; s > 0; s >>= 1) {
        if (threadIdx.x < s) red[threadIdx.x] += red[threadIdx.x + s];
        __syncthreads();
    }
    if (threadIdx.x == 0) partials[blockIdx.x] = red[0];
}

__global__ __launch_bounds__(1024) void scan_top_kernel(
    int* __restrict__ partials, int NB)
{
    __shared__ int sh[1024];
    int t = threadIdx.x;
    sh[t] = (t < NB) ? partials[t] : 0;
    __syncthreads();
    for (int s = 1; s < 1024; s <<= 1) {
        int v = (t >= s) ? sh[t - s] : 0;
        __syncthreads();
        sh[t] += v;
        __syncthreads();
    }
    if (t < NB) partials[t] = (t == 0) ? 0 : sh[t - 1];
}

__global__ __launch_bounds__(SCAN_BLOCK) void scan_final_kernel(
    const int* __restrict__ cnt, const int* __restrict__ partials,
    int* __restrict__ off, int* __restrict__ cur, int N, int E)
{
    __shared__ int sh[SCAN_BLOCK];
    int i = blockIdx.x * SCAN_BLOCK + threadIdx.x;
    int t = threadIdx.x;
    int v = (i < N) ? cnt[i] : 0;
    sh[t] = v;
    __syncthreads();
    for (int s = 1; s < SCAN_BLOCK; s <<= 1) {
        int u = (t >= s) ? sh[t - s] : 0;
        __syncthreads();
        sh[t] += u;
        __syncthreads();
    }
    int excl = partials[blockIdx.x] + sh[t] - v;
    if (i < N) { off[i] = excl; cur[i] = excl; }
    if (i == 0) off[N] = E;
}

// 4 edges/thread scatter: 4 independent atomic->store chains
__global__ __launch_bounds__(256) void rank_kernel(
    const int* __restrict__ dst,
    const int* __restrict__ src,
    const int* __restrict__ edge_type,
    const float* __restrict__ edge_norm,
    int* __restrict__ cur,
    uint2* __restrict__ pay,
    int E, int V)
{
    int base = (blockIdx.x * 256 + threadIdx.x) * 4;
    if (base >= E) return;
    if (base + 3 < E) {
        int4   d = *reinterpret_cast<const int4*>(dst + base);
        int4   s = *reinterpret_cast<const int4*>(src + base);
        int4   t = *reinterpret_cast<const int4*>(edge_type + base);
        float4 n = *reinterpret_cast<const float4*>(edge_norm + base);
        int half = E >> 1;
        int p0 = atomicAdd(&cur[d.x + (base + 0 < half ? 0 : V)], 1);
        int p1 = atomicAdd(&cur[d.y + (base + 1 < half ? 0 : V)], 1);
        int p2 = atomicAdd(&cur[d.z + (base + 2 < half ? 0 : V)], 1);
        int p3 = atomicAdd(&cur[d.w + (base + 3 < half ? 0 : V)], 1);
        pay[p0] = make_uint2(((unsigned)s.x << 16) | (unsigned)t.x, __float_as_uint(n.x));
        pay[p1] = make_uint2(((unsigned)s.y << 16) | (unsigned)t.y, __float_as_uint(n.y));
        pay[p2] = make_uint2(((unsigned)s.z << 16) | (unsigned)t.z, __float_as_uint(n.z));
        pay[p3] = make_uint2(((unsigned)s.w << 16) | (unsigned)t.w, __float_as_uint(n.w));
    } else {
        for (int e = base; e < E; ++e) {
            int key = dst[e] + (e < (E >> 1) ? 0 : V);
            int pos = atomicAdd(&cur[key], 1);
            pay[pos] = make_uint2(((unsigned)src[e] << 16) | (unsigned)edge_type[e],
                                  __float_as_uint(edge_norm[e]));
        }
    }
}

// one 32-lane group per bucket; bf16 gathers, f32 accum, bf16 store
__global__ __launch_bounds__(256) void aggregate_kernel(
    const short* __restrict__ xbf,
    const short* __restrict__ relbf,
    const uint2* __restrict__ pay,
    const int* __restrict__ off,
    short* __restrict__ accbf,       // [2V,128] = [acc_in ; acc_out]
    int NK)
{
    int gid = (blockIdx.x * 256 + threadIdx.x) >> 5;
    if (gid >= NK) return;
    int lane = threadIdx.x & 31;
    int f0 = lane << 2;

    int beg = off[gid], end = off[gid + 1];
    float a0 = 0.f, a1 = 0.f, a2 = 0.f, a3 = 0.f;

    for (int base = beg; base < end; base += 32) {
        int j = base + lane;
        uint2 p = (j < end) ? pay[j] : make_uint2(0u, 0u);
        int m = min(32, end - base);
        for (int q = 0; q < m; ++q) {
            unsigned pq = __shfl(p.x, q, 32);
            float nq = __uint_as_float(__shfl(p.y, q, 32));
            int s = (int)(pq >> 16);
            int t = (int)(pq & 0xffffu);
            uint2 xv = *reinterpret_cast<const uint2*>(xbf + (size_t)s * 128 + f0);
            uint2 rv = *reinterpret_cast<const uint2*>(relbf + (size_t)t * 128 + f0);
            a0 += bflo(xv.x) * bflo(rv.x) * nq;
            a1 += bfhi(xv.x) * bfhi(rv.x) * nq;
            a2 += bflo(xv.y) * bflo(rv.y) * nq;
            a3 += bfhi(xv.y) * bfhi(rv.y) * nq;
        }
    }
    uint2 o;
    o.x = (unsigned)(unsigned short)f2bf(a0) | ((unsigned)(unsigned short)f2bf(a1) << 16);
    o.y = (unsigned)(unsigned short)f2bf(a2) | ((unsigned)(unsigned short)f2bf(a3) << 16);
    *reinterpret_cast<uint2*>(accbf + (size_t)gid * 128 + f0) = o;
}

// pack weights into bf16 MFMA B-fragment order; loop_rel folded into loop_w
__global__ __launch_bounds__(256) void wpack_kernel(
    const float* __restrict__ in_w,
    const float* __restrict__ out_w,
    const float* __restrict__ loop_w,
    const float* __restrict__ loop_rel,
    short* __restrict__ wpack)
{
    int idx = blockIdx.x * 256 + threadIdx.x;
    if (idx >= 3 * 8 * 4 * 64) return;
    int lane = idx & 63;
    int t    = (idx >> 6) & 3;
    int cblk = (idx >> 8) & 7;
    int m    = idx >> 11;
    const float* W = (m == 0) ? in_w : (m == 1) ? out_w : loop_w;
    int col = cblk * 16 + (lane & 15);
    int kb  = t * 32 + ((lane >> 4) << 3);
    short8v v;
#pragma unroll
    for (int j = 0; j < 8; ++j) {
        float w = W[(kb + j) * 128 + col];
        if (m == 2) w *= loop_rel[kb + j];
        v[j] = f2bf(w);
    }
    *reinterpret_cast<short8v*>(wpack + (size_t)idx * 8) = v;
}

// bf16 MFMA fused GEMM + bias + /3, with BN stats (sum/sumsq per col) fused
// into the epilogue via LDS reduction + per-block global atomics.
__global__ __launch_bounds__(256) void fused_gemm_mfma_kernel(
    const short* __restrict__ accbf,     // [2V,128]
    const short* __restrict__ xbf,       // [V,128]
    const short* __restrict__ wpack,
    const float* __restrict__ bias,
    float* __restrict__ h,
    float* __restrict__ stats,           // [0:128] sum, [128:256] sumsq
    int V)
{
    __shared__ float s_red[256];         // [0:128] sum, [128:256] sumsq

    int wave = threadIdx.x >> 6;
    int lane = threadIdx.x & 63;
    int kgrp = lane >> 4;                 // 0..3
    int row0 = blockIdx.x * 64 + wave * 16;
    int rowl = row0 + (lane & 15);
    int rowc = min(rowl, V - 1);          // clamp (stores guarded)

    for (int i = threadIdx.x; i < 256; i += 256) s_red[i] = 0.f;

    float4v c[8];
#pragma unroll
    for (int b = 0; b < 8; ++b) c[b] = (float4v)(0.f);

    const short* mats[3] = { accbf, accbf + (size_t)V * 128, xbf };

    for (int m = 0; m < 3; ++m) {
        const short* A = mats[m] + (size_t)rowc * 128;
#pragma unroll
        for (int t = 0; t < 4; ++t) {
            short8v af = *reinterpret_cast<const short8v*>(A + t * 32 + (kgrp << 3));
            const short* wp = wpack + (((size_t)(m * 8) * 4 + t) * 64 + lane) * 8;
#pragma unroll
            for (int b = 0; b < 8; ++b) {
                short8v bf_ = *reinterpret_cast<const short8v*>(wp + (size_t)b * 4 * 64 * 8);
                c[b] = __builtin_amdgcn_mfma_f32_16x16x32_bf16(af, bf_, c[b], 0, 0, 0);
            }
        }
    }
    __syncthreads();   // s_red zeroed

    // epilogue: C/D layout col=lane&15, row=(lane>>4)*4+r  [m89]
#pragma unroll
    for (int b = 0; b < 8; ++b) {
        int col = b * 16 + (lane & 15);
        float bv = bias[col];
        float ps = 0.f, pq = 0.f;
#pragma unroll
        for (int r = 0; r < 4; ++r) {
            int row = row0 + kgrp * 4 + r;
            if (row < V) {
                float v = c[b][r] * (1.f / 3.f) + bv;
                h[(size_t)row * 128 + col] = v;
                ps += v;
                pq += v * v;
            }
        }
        atomicAdd(&s_red[col], ps);
        atomicAdd(&s_red[128 + col], pq);
    }
    __syncthreads();
    if (threadIdx.x < 256)
        atomicAdd(&stats[threadIdx.x], s_red[threadIdx.x]);
}

__global__ __launch_bounds__(256) void bn_apply_kernel(
    float* __restrict__ h,
    const float* __restrict__ stats,
    const float* __restrict__ gamma,
    const float* __restrict__ beta,
    int V)
{
    int col = threadIdx.x & 127;
    int rg  = threadIdx.x >> 7;
    float inv_v = 1.f / (float)V;
    float mean = stats[col] * inv_v;
    float var  = stats[128 + col] * inv_v - mean * mean;
    float sc = rsqrtf(var + 1e-5f) * gamma[col];
    float sh = beta[col] - mean * sc;
    for (int row = blockIdx.x * 2 + rg; row < V; row += gridDim.x * 2) {
        float v = h[(size_t)row * 128 + col];
        v = v * sc + sh;
        h[(size_t)row * 128 + col] = v > 0.f ? v : 0.f;
    }
}

__global__ __launch_bounds__(256) void rel_gemm_kernel(
    const float* __restrict__ rel,
    const float* __restrict__ w_rel,
    float* __restrict__ out_rel,
    int R)
{
    int col = threadIdx.x & 127;
    int row = blockIdx.x * 2 + (threadIdx.x >> 7);
    if (row >= R) return;
    float acc = 0.f;
    for (int k = 0; k < 128; ++k)
        acc += rel[row * 128 + k] * w_rel[k * 128 + col];
    out_rel[row * 128 + col] = acc;
}

extern "C" void kernel_launch(void* const* d_in, const int* in_sizes, int n_in,
                              void* d_out, int out_size, void* d_ws, size_t ws_size,
                              hipStream_t stream)
{
    const float* x         = (const float*)d_in[0];
    const float* rel_repr  = (const float*)d_in[1];
    const float* edge_norm = (const float*)d_in[2];
    const float* in_w      = (const float*)d_in[3];
    const float* out_w     = (const float*)d_in[4];
    const float* loop_w    = (const float*)d_in[5];
    const float* w_rel     = (const float*)d_in[6];
    const float* loop_rel  = (const float*)d_in[7];
    const float* bias      = (const float*)d_in[8];
    const float* bn_gamma  = (const float*)d_in[9];
    const float* bn_beta   = (const float*)d_in[10];
    const int* edge_type   = (const int*)d_in[11];
    const int* src         = (const int*)d_in[12];
    const int* dst         = (const int*)d_in[13];

    const int V = in_sizes[0] / 128;     // 50000
    const int E = in_sizes[2];           // 800000
    const int R = in_sizes[1] / 128;     // 200
    const int NK = 2 * V;                // buckets: [dst(in) ; dst(out)]
    const int NB = (NK + SCAN_BLOCK - 1) / SCAN_BLOCK;

    float* h       = (float*)d_out;              // [V,128]
    float* out_rel = h + (size_t)V * 128;        // [R,128]

    // workspace layout (manual, 16B-aligned where vector-loaded)
    char* wp_ = (char*)d_ws;
    short* accbf   = (short*)wp_;  wp_ += (size_t)NK * 128 * sizeof(short);
    short* xbf     = (short*)wp_;  wp_ += (size_t)V * 128 * sizeof(short);
    short* relbf   = (short*)wp_;  wp_ += (size_t)R * 128 * sizeof(short);
    short* wpack   = (short*)wp_;  wp_ += (size_t)3 * 8 * 4 * 64 * 8 * sizeof(short);
    float* stats   = (float*)wp_;  wp_ += 256 * sizeof(float);
    int*   cnt     = (int*)wp_;    wp_ += (size_t)NK * sizeof(int);
    int*   off     = (int*)wp_;    wp_ += ((size_t)NK + 1) * sizeof(int);
    int*   cur     = (int*)wp_;    wp_ += (size_t)NK * sizeof(int);
    int*   partials= (int*)wp_;    wp_ += 1024 * sizeof(int);
    wp_ = (char*)(((uintptr_t)wp_ + 15) & ~(uintptr_t)15);
    uint2* pay     = (uint2*)wp_;

    // zero stats + cnt (adjacent); accbf fully written by aggregate
    hipMemsetAsync(stats, 0, 256 * sizeof(float) + (size_t)NK * sizeof(int), stream);

    {
        size_t total = ((size_t)(V + R) * 128) / 8;
        xcast_kernel<<<(int)((total + 255) / 256), 256, 0, stream>>>(
            x, rel_repr, xbf, relbf, V, R);
    }
    wpack_kernel<<<(3 * 8 * 4 * 64 + 255) / 256, 256, 0, stream>>>(
        in_w, out_w, loop_w, loop_rel, wpack);

    int eb4 = (E + 1023) / 1024;   // 4 edges/thread
    hist_kernel<<<eb4, 256, 0, stream>>>(dst, cnt, E, V);
    scan_partial_kernel<<<NB, SCAN_BLOCK, 0, stream>>>(cnt, partials, NK);
    scan_top_kernel<<<1, 1024, 0, stream>>>(partials, NB);
    scan_final_kernel<<<NB, SCAN_BLOCK, 0, stream>>>(cnt, partials, off, cur, NK, E);
    rank_kernel<<<eb4, 256, 0, stream>>>(dst, src, edge_type, edge_norm, cur, pay, E, V);
    aggregate_kernel<<<(NK * 32 + 255) / 256, 256, 0, stream>>>(
        xbf, relbf, pay, off, accbf, NK);

    fused_gemm_mfma_kernel<<<(V + 63) / 64, 256, 0, stream>>>(
        accbf, xbf, wpack, bias, h, stats, V);

    bn_apply_kernel<<<1024, 256, 0, stream>>>(h, stats, bn_gamma, bn_beta, V);
    rel_gemm_kernel<<<(R + 1) / 2, 256, 0, stream>>>(rel_repr, w_rel, out_rel, R);
}